// Round 1
// baseline (170.206 us; speedup 1.0000x reference)
//
#include <hip/hip_runtime.h>

#define NBINS 12
#define GRID1 2048
#define BLK 256

// Kernel 1: per-block partial reductions.
//  - sumsq partial: sum(x^2 + t^2) over this block's elements
//  - cross partials: per-graph sum of <x_i, t_i>
// Layout: 16 threads per node (each thread one float4 of the 64-dim row).
// ws layout: ws[block*16 + g] = cross_g partial (g<12), ws[block*16 + 12] = sumsq partial.
__global__ __launch_bounds__(BLK) void umse_partial(
    const float4* __restrict__ x4, const float4* __restrict__ t4,
    const int* __restrict__ batch32, float* __restrict__ blockOut,
    int nNodes)
{
    __shared__ float cross_lds[NBINS];
    __shared__ float wsum[BLK / 64];
    __shared__ int s_is64;

    const int tid = threadIdx.x;
    if (tid < NBINS) cross_lds[tid] = 0.0f;
    if (tid == 0) {
        // int32 batch: last element is 11 (a.s.). int64 batch viewed as int32:
        // slot nNodes-1 is the high word of a mid-array element -> 0.
        s_is64 = (batch32[nNodes - 1] == 0) ? 1 : 0;
    }
    __syncthreads();
    const int is64 = s_is64;

    const long total  = (long)nNodes * 16;             // float4 groups (D=64 -> 16/node)
    const long stride = (long)GRID1 * BLK;
    long idx = (long)blockIdx.x * BLK + tid;
    const long iters = (total + stride - 1) / stride;  // uniform across all threads

    float sumsq = 0.0f;
    const int lane = tid & 63;

    for (long it = 0; it < iters; ++it, idx += stride) {
        float p = 0.0f;
        if (idx < total) {
            float4 a = x4[idx];
            float4 b = t4[idx];
            p = a.x * b.x + a.y * b.y + a.z * b.z + a.w * b.w;
            sumsq += a.x * a.x + a.y * a.y + a.z * a.z + a.w * a.w
                   + b.x * b.x + b.y * b.y + b.z * b.z + b.w * b.w;
        }
        // reduce dot over the 16 lanes owning this node (xor masks stay in-group)
        p += __shfl_xor(p, 1);
        p += __shfl_xor(p, 2);
        p += __shfl_xor(p, 4);
        p += __shfl_xor(p, 8);
        if ((lane & 15) == 0 && idx < total) {
            long node = idx >> 4;
            int g = is64 ? batch32[(int)(node << 1)] : batch32[(int)node];
            atomicAdd(&cross_lds[g], p);
        }
    }

    __syncthreads();  // all LDS atomics done

    // block-reduce sumsq: wave shuffle then cross-wave via LDS
    for (int m = 32; m; m >>= 1) sumsq += __shfl_xor(sumsq, m);
    const int wid = tid >> 6;
    if (lane == 0) wsum[wid] = sumsq;
    __syncthreads();

    float* dst = blockOut + (long)blockIdx.x * 16;
    if (tid == 0) {
        float s = 0.0f;
        for (int w = 0; w < BLK / 64; ++w) s += wsum[w];
        dst[12] = s;
    }
    if (tid < NBINS) dst[tid] = cross_lds[tid];
}

// Kernel 2: reduce per-block partials (fp64), combine into the scalar loss.
__global__ __launch_bounds__(BLK) void umse_final(
    const float* __restrict__ blockOut, float* __restrict__ out, int G)
{
    __shared__ double cols[16];
    const int tid = threadIdx.x;
    const int wid = tid >> 6, lane = tid & 63;

    // 4 waves cover 13 columns: wid, wid+4, wid+8 (and wave0 also 12)
    for (int c = wid; c < 13; c += 4) {
        double s = 0.0;
        for (int b = lane; b < G; b += 64) s += (double)blockOut[(long)b * 16 + c];
        for (int m = 32; m; m >>= 1) s += __shfl_xor(s, m);
        if (lane == 0) cols[c] = s;
    }
    __syncthreads();

    if (tid == 0) {
        double sum = cols[12];
        double acc = 0.0;
        for (int g = 0; g < NBINS; ++g) acc += fabs(cols[g]);
        out[0] = (float)(sum - 2.0 * acc);
    }
}

extern "C" void kernel_launch(void* const* d_in, const int* in_sizes, int n_in,
                              void* d_out, int out_size, void* d_ws, size_t ws_size,
                              hipStream_t stream)
{
    const float* x = (const float*)d_in[0];
    const float* t = (const float*)d_in[1];
    const int* batch = (const int*)d_in[2];
    const int nNodes = in_sizes[2];   // N = 262144
    float* ws = (float*)d_ws;
    float* out = (float*)d_out;

    umse_partial<<<GRID1, BLK, 0, stream>>>(
        (const float4*)x, (const float4*)t, batch, ws, nNodes);
    umse_final<<<1, BLK, 0, stream>>>(ws, out, GRID1);
}

// Round 2
// 160.800 us; speedup vs baseline: 1.0585x; 1.0585x over previous
//
#include <hip/hip_runtime.h>

#define NBINS 12
#define GRID1 2048
#define BLK 256

// Reduce a 16-lane node-group's partial dot and atomically add into the LDS bin.
// Caller must guarantee the 16-lane group is uniformly active with uniform g.
__device__ __forceinline__ void flush_group(float acc, int g, float* cross_lds, int lane) {
    acc += __shfl_xor(acc, 1);
    acc += __shfl_xor(acc, 2);
    acc += __shfl_xor(acc, 4);
    acc += __shfl_xor(acc, 8);
    if ((lane & 15) == 0) atomicAdd(&cross_lds[g], acc);
}

// Kernel 1: per-block partial reductions over a CONTIGUOUS float4 chunk.
// ws layout (column-major for coalesced final reduce):
//   ws[g*GRID1 + block]  = cross_g partial (g<12)
//   ws[12*GRID1 + block] = sumsq partial
// FULL=true: chunk size divisible by BLK (no bounds checks, grouped flush).
template <bool FULL>
__global__ __launch_bounds__(BLK) void umse_partial(
    const float4* __restrict__ x4, const float4* __restrict__ t4,
    const int* __restrict__ batch32, float* __restrict__ ws, int nNodes)
{
    __shared__ float cross_lds[NBINS];
    __shared__ float wsum[BLK / 64];
    __shared__ int s_is64;

    const int tid = threadIdx.x;
    if (tid < NBINS) cross_lds[tid] = 0.0f;
    if (tid == 0) {
        // int32 batch: last slot is 11. int64 viewed as int32: slot nNodes-1
        // is the high word of a mid-array element -> 0.
        s_is64 = (batch32[nNodes - 1] == 0) ? 1 : 0;
    }
    __syncthreads();
    const int is64 = s_is64;
    const int lane = tid & 63;

    const int total = nNodes * 16;                       // float4 count (D=64)
    const int per_block = (total + GRID1 - 1) / GRID1;   // contiguous chunk
    const int start = blockIdx.x * per_block;
    const int end = min(start + per_block, total);

    float sumsq = 0.0f;
    float acc = 0.0f;     // running dot partial for current graph
    int curg = -1;

    if (FULL) {
        for (int idx = start + tid; idx < end; idx += BLK) {
            float4 a = x4[idx];
            float4 b = t4[idx];
            int node = idx >> 4;
            int g = is64 ? batch32[node << 1] : batch32[node];
            sumsq += a.x*a.x + a.y*a.y + a.z*a.z + a.w*a.w
                   + b.x*b.x + b.y*b.y + b.z*b.z + b.w*b.w;
            float p = a.x*b.x + a.y*b.y + a.z*b.z + a.w*b.w;
            if (g != curg) {                 // uniform within each 16-lane group
                if (curg >= 0) flush_group(acc, curg, cross_lds, lane);
                curg = g;
                acc = p;
            } else {
                acc += p;
            }
        }
        if (curg >= 0) flush_group(acc, curg, cross_lds, lane);
    } else {
        // generic fallback: guarded loads, per-thread flush (no shuffles)
        for (int base = start; base < end; base += BLK) {
            int idx = base + tid;
            if (idx >= end) continue;
            float4 a = x4[idx];
            float4 b = t4[idx];
            int node = idx >> 4;
            int g = is64 ? batch32[node << 1] : batch32[node];
            sumsq += a.x*a.x + a.y*a.y + a.z*a.z + a.w*a.w
                   + b.x*b.x + b.y*b.y + b.z*b.z + b.w*b.w;
            float p = a.x*b.x + a.y*b.y + a.z*b.z + a.w*b.w;
            if (g != curg) {
                if (curg >= 0) atomicAdd(&cross_lds[curg], acc);
                curg = g;
                acc = p;
            } else {
                acc += p;
            }
        }
        if (curg >= 0) atomicAdd(&cross_lds[curg], acc);
    }

    // block-reduce sumsq
    for (int m = 32; m; m >>= 1) sumsq += __shfl_xor(sumsq, m);
    if (lane == 0) wsum[tid >> 6] = sumsq;
    __syncthreads();

    if (tid == 0) {
        float s = 0.0f;
        for (int w = 0; w < BLK / 64; ++w) s += wsum[w];
        ws[12 * GRID1 + blockIdx.x] = s;
    }
    if (tid < NBINS) ws[tid * GRID1 + blockIdx.x] = cross_lds[tid];
}

// Kernel 2: 13 waves, wave w reduces column w (contiguous, coalesced), fp64.
__global__ __launch_bounds__(832) void umse_final(
    const float* __restrict__ ws, float* __restrict__ out)
{
    __shared__ double cols[13];
    const int tid = threadIdx.x;
    const int w = tid >> 6, lane = tid & 63;

    double s = 0.0;
    for (int b = lane; b < GRID1; b += 64) s += (double)ws[w * GRID1 + b];
    for (int m = 32; m; m >>= 1) s += __shfl_xor(s, m);
    if (lane == 0) cols[w] = s;
    __syncthreads();

    if (tid == 0) {
        double acc = 0.0;
        for (int g = 0; g < NBINS; ++g) acc += fabs(cols[g]);
        out[0] = (float)(cols[12] - 2.0 * acc);
    }
}

extern "C" void kernel_launch(void* const* d_in, const int* in_sizes, int n_in,
                              void* d_out, int out_size, void* d_ws, size_t ws_size,
                              hipStream_t stream)
{
    const float* x = (const float*)d_in[0];
    const float* t = (const float*)d_in[1];
    const int* batch = (const int*)d_in[2];
    const int nNodes = in_sizes[2];   // N = 262144
    float* ws = (float*)d_ws;
    float* out = (float*)d_out;

    const long total = (long)nNodes * 16;
    const int per_block = (int)((total + GRID1 - 1) / GRID1);
    const bool full = (total % GRID1 == 0) && (per_block % BLK == 0);

    if (full) {
        umse_partial<true><<<GRID1, BLK, 0, stream>>>(
            (const float4*)x, (const float4*)t, batch, ws, nNodes);
    } else {
        umse_partial<false><<<GRID1, BLK, 0, stream>>>(
            (const float4*)x, (const float4*)t, batch, ws, nNodes);
    }
    umse_final<<<1, 832, 0, stream>>>(ws, out);
}